// Round 6
// baseline (572.626 us; speedup 1.0000x reference)
//
#include <hip/hip_runtime.h>

// Problem constants (from reference)
#define DCOLS 32        // dist/angle columns
#define WCOLS 32        // idx_t/index_t columns
#define NUM_CLASSES 22
#define ONEHOT_COLS (NUM_CLASSES * WCOLS)       // 704
#define OUT_COLS (ONEHOT_COLS + WCOLS + WCOLS)  // 768
#define ROWS_PER_BLOCK 8                        // 8 rows x 32 cols = 256 gather threads

// native clang vector type — __builtin_nontemporal_store requires it
typedef float vfloat4 __attribute__((ext_vector_type(4)));

// ---------------------------------------------------------------------------
// Min/max encoding (ws[0..1] seeded with 0xFF bytes by hipMemsetAsync):
//   ws[0] (uint): running MIN of bits(-v); v>=0 -> -v is a negative float;
//     uint order on negative floats is reversed float order -> uint-min
//     tracks float-min.  Seed 0xFFFFFFFF >= everything.
//   ws[1] (int):  running MAX of bits(v); v>=0 -> int order == float order.
//     Seed 0xFFFFFFFF == -1 <= everything.
// Recover: dmin = -as_float(ws[0]);  dmax = as_float(ws[1]).
//
// R5 lesson (counters): FETCH is only ~26 MB (reads are cache-absorbed);
// WRITE 300 MB dominates, and write BW needs many independent blocks —
// the 1024-block grid.sync() fusion ran at 1.55 TB/s. So: two kernels,
// 12500 independent blocks each, no serial minmax pre-pass. Kernel A
// stashes the raw gathered dist contiguously in ws; kernel B normalizes.

// ---------------------------------------------------------------------------
// Kernel A: 8 rows per 256-thread block.
//  - every thread gathers one (dist, angle) pair; raw dist goes to the
//    contiguous stash (coalesced 1 KB/block) and into the min/max reduce
//  - writes one-hot (cols 0..703) + angle (cols 736..767): 184 of 192
//    float4s per row, contiguous nontemporal dwordx4 stores
//  - one atomicMin/atomicMax pair per block
__global__ __launch_bounds__(256) void fill_a_kernel(
    const float* __restrict__ dist,
    const float* __restrict__ angle,
    const int*   __restrict__ idx_t,
    const int*   __restrict__ index_t,
    const int*   __restrict__ index_h,
    unsigned*    __restrict__ ws,
    float*       __restrict__ stash,
    float*       __restrict__ out,
    int H)
{
    const int h0  = blockIdx.x * ROWS_PER_BLOCK;
    const int tid = threadIdx.x;

    __shared__ int   s_idx[ROWS_PER_BLOCK][WCOLS];
    __shared__ float s_angle[ROWS_PER_BLOCK][WCOLS];
    __shared__ float smin[4], smax[4];

    float vmin = __int_as_float(0x7f800000);  // +inf
    float vmax = 0.0f;
    {
        const int r = tid >> 5;
        const int c = tid & 31;
        const int h = h0 + r;
        float dv = 0.0f, av = 0.0f;
        int   ii = 0;
        if (h < H) {
            ii = idx_t[h * WCOLS + c];
            const int it = index_t[h * WCOLS + c];
            if (it < DCOLS) {
                const int base = index_h[h] * DCOLS;
                dv = dist[base + it];
                av = angle[base + it];
            }
            vmin = fminf(vmin, dv);
            vmax = fmaxf(vmax, dv);
            stash[h * WCOLS + c] = dv;     // raw value; kernel B normalizes
        }
        s_idx[r][c]   = ii;
        s_angle[r][c] = av;
    }
    __syncthreads();

    const bool full = (h0 + ROWS_PER_BLOCK) <= H;
    #pragma unroll
    for (int m = 0; m < 6; ++m) {
        const int t    = m * 256 + tid;    // 0..1535 across the block
        const int row  = t / 192;          // const-div -> mul/shift
        const int col4 = t - row * 192;
        if (col4 >= 176 && col4 < 184) continue;   // dist region -> kernel B
        const int j0 = col4 * 4;
        vfloat4 v4;
        #pragma unroll
        for (int k = 0; k < 4; ++k) {
            const int j = j0 + k;
            float v;
            if (j < ONEHOT_COLS) {
                const int w  = j / NUM_CLASSES;
                const int cc = j - w * NUM_CLASSES;
                v = (s_idx[row][w] == cc) ? 1.0f : 0.0f;
            } else {
                v = s_angle[row][j - (ONEHOT_COLS + WCOLS)];
            }
            v4[k] = v;
        }
        if (full || (h0 + row) < H) {
            vfloat4* o = reinterpret_cast<vfloat4*>(
                out + (size_t)(h0 + row) * OUT_COLS);
            __builtin_nontemporal_store(v4, o + col4);
        }
    }

    // block min/max reduce -> one atomic pair
    #pragma unroll
    for (int off = 32; off > 0; off >>= 1) {
        vmin = fminf(vmin, __shfl_down(vmin, off, 64));
        vmax = fmaxf(vmax, __shfl_down(vmax, off, 64));
    }
    const int lane = tid & 63;
    const int wave = tid >> 6;
    if (lane == 0) { smin[wave] = vmin; smax[wave] = vmax; }
    __syncthreads();
    if (tid == 0) {
        float m = smin[0], M = smax[0];
        #pragma unroll
        for (int k = 1; k < 4; ++k) { m = fminf(m, smin[k]); M = fmaxf(M, smax[k]); }
        atomicMin(ws,             __float_as_uint(-m));
        atomicMax((int*)(ws + 1), __float_as_int(M));
    }
}

// ---------------------------------------------------------------------------
// Kernel B: normalize the stashed dist values and write cols 704..735.
// 12.8 MB read (contiguous) + 12.8 MB write (128 B runs per row).
__global__ __launch_bounds__(256) void fill_b_kernel(
    const float*    __restrict__ stash,
    const unsigned* __restrict__ ws,
    float*          __restrict__ out,
    int total4)   // H * WCOLS / 4
{
    const int i = blockIdx.x * blockDim.x + threadIdx.x;
    if (i >= total4) return;
    const float dmin = -__uint_as_float(ws[0]);
    const float dmax =  __uint_as_float(ws[1]);
    const float inv  = 1.0f / (dmax - dmin);

    vfloat4 v = reinterpret_cast<const vfloat4*>(stash)[i];
    v = (v - dmin) * inv;
    const int row  = i >> 3;    // 8 float4s per row
    const int col4 = i & 7;
    vfloat4* o = reinterpret_cast<vfloat4*>(out + (size_t)row * OUT_COLS);
    __builtin_nontemporal_store(v, o + 176 + col4);
}

// ---------------------------------------------------------------------------
extern "C" void kernel_launch(void* const* d_in, const int* in_sizes, int n_in,
                              void* d_out, int out_size, void* d_ws, size_t ws_size,
                              hipStream_t stream) {
    const float* dist    = (const float*)d_in[0];
    const float* angle   = (const float*)d_in[1];
    const int*   idx_t   = (const int*)d_in[2];
    const int*   index_t = (const int*)d_in[3];
    const int*   index_h = (const int*)d_in[4];
    float*       out     = (float*)d_out;
    unsigned*    ws      = (unsigned*)d_ws;
    float*       stash   = (float*)((char*)d_ws + 256);   // raw dist stash
    const int    H       = in_sizes[4];       // index_h has H elements

    // Seed both min/max accumulators with 0xFFFFFFFF (see encoding above).
    (void)hipMemsetAsync(ws, 0xFF, 8, stream);

    const int blocks_a = (H + ROWS_PER_BLOCK - 1) / ROWS_PER_BLOCK;
    hipLaunchKernelGGL(fill_a_kernel, dim3(blocks_a), dim3(256), 0, stream,
                       dist, angle, idx_t, index_t, index_h, ws, stash, out, H);

    const int total4   = (H * WCOLS) / 4;
    const int blocks_b = (total4 + 255) / 256;
    hipLaunchKernelGGL(fill_b_kernel, dim3(blocks_b), dim3(256), 0, stream,
                       stash, ws, out, total4);
}

// Round 7
// 393.881 us; speedup vs baseline: 1.4538x; 1.4538x over previous
//
#include <hip/hip_runtime.h>

// Problem constants (from reference)
#define DCOLS 32        // dist/angle columns
#define WCOLS 32        // idx_t/index_t columns
#define NUM_CLASSES 22
#define ONEHOT_COLS (NUM_CLASSES * WCOLS)       // 704
#define OUT_COLS (ONEHOT_COLS + WCOLS + WCOLS)  // 768
#define ROWS_A 8                                // kernel A: 8 rows x 32 cols
#define ROWS_B 4                                // kernel B: 4 rows x 64 cols

// native clang vector type — __builtin_nontemporal_store requires it
typedef float vfloat4 __attribute__((ext_vector_type(4)));

// ---------------------------------------------------------------------------
// Min/max encoding (ws[0..1] seeded with 0xFF bytes by hipMemsetAsync):
//   ws[0] (uint): running MIN of bits(-v); v>=0 -> uint-min tracks float-min.
//   ws[1] (int):  running MAX of bits(v);  v>=0 -> int order == float order.
// Recover: dmin = -as_float(ws[0]);  dmax = as_float(ws[1]).
//
// R6 lesson: the 300 MB writer must be byte-dense, atomic-free, gather-free.
// Split by dependency: A = pure one-hot streamer (92% of bytes, depends only
// on idx_t); M = small minmax (proven R4 shape, 2048 atomics); B = gather +
// normalize overwrite of cols 704..767 (25.6 MB).

// ---------------------------------------------------------------------------
// Kernel A: pure one-hot writer. 8 rows per 256-thread block.
// Loads one coalesced idx_t row-block (1 KB), stores 6x256 float4 = 24 KB
// fully contiguous nontemporal stores (cols 704..767 get placeholder zeros,
// overwritten by kernel B).
__global__ __launch_bounds__(256) void onehot_kernel(
    const int* __restrict__ idx_t,
    float*     __restrict__ out,
    int H)
{
    const int h0  = blockIdx.x * ROWS_A;
    const int tid = threadIdx.x;

    __shared__ int s_idx[ROWS_A][WCOLS];
    {
        const int r = tid >> 5;
        const int c = tid & 31;
        const int h = h0 + r;
        s_idx[r][c] = (h < H) ? idx_t[h * WCOLS + c] : 0;
    }
    __syncthreads();

    const bool full = (h0 + ROWS_A) <= H;
    #pragma unroll
    for (int m = 0; m < 6; ++m) {
        const int t    = m * 256 + tid;    // 0..1535 across the block
        const int row  = t / 192;          // const-div -> mul/shift
        const int col4 = t - row * 192;
        const int j0   = col4 * 4;
        vfloat4 v4;
        #pragma unroll
        for (int k = 0; k < 4; ++k) {
            const int j = j0 + k;
            float v = 0.0f;                // cols >= 704: placeholder
            if (j < ONEHOT_COLS) {
                const int w  = j / NUM_CLASSES;
                const int cc = j - w * NUM_CLASSES;
                v = (s_idx[row][w] == cc) ? 1.0f : 0.0f;
            }
            v4[k] = v;
        }
        if (full) {
            vfloat4* o = reinterpret_cast<vfloat4*>(out + (size_t)h0 * OUT_COLS);
            __builtin_nontemporal_store(v4, o + t);
        } else if (h0 + row < H) {
            vfloat4* o = reinterpret_cast<vfloat4*>(
                out + (size_t)(h0 + row) * OUT_COLS);
            __builtin_nontemporal_store(v4, o + col4);
        }
    }
}

// ---------------------------------------------------------------------------
// Kernel M: global min/max over gathered dist_t (R4-proven shape: 1024 blocks,
// int4 index loads, wave reduce, 2048 total atomics).
__global__ __launch_bounds__(256) void minmax_kernel(
    const float* __restrict__ dist,
    const int*   __restrict__ index_t,
    const int*   __restrict__ index_h,
    unsigned*    __restrict__ ws,
    int total4)  // total4 = H * WCOLS / 4
{
    float vmin = __int_as_float(0x7f800000);  // +inf
    float vmax = 0.0f;
    const int stride = gridDim.x * blockDim.x;
    for (int i4 = blockIdx.x * blockDim.x + threadIdx.x; i4 < total4; i4 += stride) {
        const int4 it = reinterpret_cast<const int4*>(index_t)[i4];
        const int  h  = i4 >> 3;              // (i4*4) >> 5
        const int  row = index_h[h] * DCOLS;
        float v0 = 0.0f, v1 = 0.0f, v2 = 0.0f, v3 = 0.0f;
        if (it.x < DCOLS) v0 = dist[row + it.x];
        if (it.y < DCOLS) v1 = dist[row + it.y];
        if (it.z < DCOLS) v2 = dist[row + it.z];
        if (it.w < DCOLS) v3 = dist[row + it.w];
        vmin = fminf(fminf(fminf(vmin, v0), fminf(v1, v2)), v3);
        vmax = fmaxf(fmaxf(fmaxf(vmax, v0), fmaxf(v1, v2)), v3);
    }
    #pragma unroll
    for (int off = 32; off > 0; off >>= 1) {
        vmin = fminf(vmin, __shfl_down(vmin, off, 64));
        vmax = fmaxf(vmax, __shfl_down(vmax, off, 64));
    }
    __shared__ float smin[4], smax[4];
    const int lane = threadIdx.x & 63;
    const int wave = threadIdx.x >> 6;
    if (lane == 0) { smin[wave] = vmin; smax[wave] = vmax; }
    __syncthreads();
    if (threadIdx.x == 0) {
        float m = smin[0], M = smax[0];
        #pragma unroll
        for (int k = 1; k < 4; ++k) { m = fminf(m, smin[k]); M = fmaxf(M, smax[k]); }
        atomicMin(ws,             __float_as_uint(-m));
        atomicMax((int*)(ws + 1), __float_as_int(M));
    }
}

// ---------------------------------------------------------------------------
// Kernel B: gather + normalize, overwriting cols 704..767 (25.6 MB).
// 4 rows per 256-thread block; thread t -> row = t>>6, cc = t&63.
// Each wave's 64 lanes cover one row's 64 output cols = 256 B contiguous.
__global__ __launch_bounds__(256) void gather_kernel(
    const float* __restrict__ dist,
    const float* __restrict__ angle,
    const int*   __restrict__ index_t,
    const int*   __restrict__ index_h,
    const unsigned* __restrict__ ws,
    float*       __restrict__ out,
    int H)
{
    const int tid = threadIdx.x;
    const int h   = blockIdx.x * ROWS_B + (tid >> 6);
    const int cc  = tid & 63;          // 0..31 dist col, 32..63 angle col
    if (h >= H) return;

    const float dmin = -__uint_as_float(ws[0]);
    const float dmax =  __uint_as_float(ws[1]);
    const float inv  = 1.0f / (dmax - dmin);

    const int it = index_t[h * WCOLS + (cc & 31)];
    float v = 0.0f;
    if (it < DCOLS) {
        const int base = index_h[h] * DCOLS;
        v = (cc < 32) ? dist[base + it] : angle[base + it];
    }
    if (cc < 32) v = (v - dmin) * inv;
    __builtin_nontemporal_store(
        v, out + (size_t)h * OUT_COLS + ONEHOT_COLS + cc);
}

// ---------------------------------------------------------------------------
extern "C" void kernel_launch(void* const* d_in, const int* in_sizes, int n_in,
                              void* d_out, int out_size, void* d_ws, size_t ws_size,
                              hipStream_t stream) {
    const float* dist    = (const float*)d_in[0];
    const float* angle   = (const float*)d_in[1];
    const int*   idx_t   = (const int*)d_in[2];
    const int*   index_t = (const int*)d_in[3];
    const int*   index_h = (const int*)d_in[4];
    float*       out     = (float*)d_out;
    unsigned*    ws      = (unsigned*)d_ws;
    const int    H       = in_sizes[4];       // index_h has H elements

    // Seed min/max accumulators with 0xFFFFFFFF (see encoding above).
    (void)hipMemsetAsync(ws, 0xFF, 8, stream);

    // M first (small, 1024 blocks), then the big streamer, then the overwrite.
    const int total4 = (H * WCOLS) / 4;
    hipLaunchKernelGGL(minmax_kernel, dim3(1024), dim3(256), 0, stream,
                       dist, index_t, index_h, ws, total4);

    const int blocks_a = (H + ROWS_A - 1) / ROWS_A;
    hipLaunchKernelGGL(onehot_kernel, dim3(blocks_a), dim3(256), 0, stream,
                       idx_t, out, H);

    const int blocks_b = (H + ROWS_B - 1) / ROWS_B;
    hipLaunchKernelGGL(gather_kernel, dim3(blocks_b), dim3(256), 0, stream,
                       dist, angle, index_t, index_h, ws, out, H);
}